// Round 17
// baseline (209.027 us; speedup 1.0000x reference)
//
#include <hip/hip_runtime.h>

#define NEG_SLOPE 0.2f
#define EPS_F 1e-16f
#define STILE 4096

typedef short short8 __attribute__((ext_vector_type(8)));
typedef float f32x4 __attribute__((ext_vector_type(4)));

// round-to-nearest-even f32 -> bf16 (finite inputs)
__device__ __forceinline__ unsigned short f2bf(float x) {
    unsigned u = __float_as_uint(x);
    return (unsigned short)((u + 0x7FFFu + ((u >> 16) & 1u)) >> 16);
}
__device__ __forceinline__ float bflo(unsigned q) { return __uint_as_float(q << 16); }
__device__ __forceinline__ float bfhi(unsigned q) { return __uint_as_float(q & 0xFFFF0000u); }

// ================= device bodies =================

// Split-column GEMM body: block covers rows [rowblk*64,+64) x cols [bh*HALF,+HALF),
// where HALF = MB/2 = one head's columns. LDS stages only that half of Wt
// (~34 KB -> 4 blocks/CU). Alpha epilogue covers exactly head bh.
template<int MB, int K, typename TIN>
__device__ __forceinline__ void gemm_body(
        const TIN* __restrict__ X, const unsigned short* __restrict__ Wt,
        unsigned short* __restrict__ Y, float* __restrict__ as_out,
        float* __restrict__ ad_out, const float* __restrict__ a_srcf,
        const float* __restrict__ a_dstf, int N, int rowblk, int bh,
        unsigned short* lds) {
    constexpr int HALF = MB / 2;
    constexpr int NT_  = HALF / 16;
    constexpr int KS   = K / 32;
    constexpr int KP   = K + 8;
    int tid  = threadIdx.x;
    int w    = tid >> 6, lane = tid & 63;
    int li   = lane & 15, kc = lane >> 4;
    int n0   = rowblk * 64 + w * 16;
    int arow = min(n0 + li, N - 1);
    const unsigned short* wsrc = Wt + (size_t)bh * HALF * K;

    // stage this half's Wt rows -> LDS (padded rows)
    constexpr int CHUNKS = HALF * K / 8;
#pragma unroll
    for (int c = 0; c < CHUNKS / 256; ++c) {
        int id = tid + c * 256;
        int m = id / (K / 8), k8 = id % (K / 8);
        *(uint4*)&lds[m * KP + k8 * 8] = *(const uint4*)&wsrc[m * K + k8 * 8];
    }
    // prefetch A slice into regs
    short8 a[KS];
#pragma unroll
    for (int ks = 0; ks < KS; ++ks) {
        if constexpr (sizeof(TIN) == 4) {
            const float* xp = (const float*)X + (size_t)arow * K + ks * 32 + kc * 8;
            float4 xa = *(const float4*)xp;
            float4 xb = *(const float4*)(xp + 4);
            a[ks][0] = (short)f2bf(xa.x); a[ks][1] = (short)f2bf(xa.y);
            a[ks][2] = (short)f2bf(xa.z); a[ks][3] = (short)f2bf(xa.w);
            a[ks][4] = (short)f2bf(xb.x); a[ks][5] = (short)f2bf(xb.y);
            a[ks][6] = (short)f2bf(xb.z); a[ks][7] = (short)f2bf(xb.w);
        } else {
            a[ks] = *(const short8*)((const unsigned short*)X + (size_t)arow * K + ks * 32 + kc * 8);
        }
    }
    __syncthreads();

    f32x4 acc[NT_];
#pragma unroll
    for (int ct = 0; ct < NT_; ++ct) acc[ct] = (f32x4){0.f, 0.f, 0.f, 0.f};
#pragma unroll
    for (int ct = 0; ct < NT_; ++ct) {
        const unsigned short* wb = lds + (ct * 16 + li) * KP + kc * 8;
#pragma unroll
        for (int ks = 0; ks < KS; ++ks) {
            short8 b = *(const short8*)(wb + ks * 32);
            acc[ct] = __builtin_amdgcn_mfma_f32_16x16x32_bf16(a[ks], b, acc[ct], 0, 0, 0);
        }
    }

    // alpha vectors for this head's column slots
    float av[NT_], dv[NT_];
#pragma unroll
    for (int ct = 0; ct < NT_; ++ct) {
        av[ct] = a_srcf[bh * HALF + ct * 16 + li];
        dv[ct] = a_dstf[bh * HALF + ct * 16 + li];
    }
    int row_base = n0 + kc * 4;
#pragma unroll
    for (int r = 0; r < 4; ++r) {
        int n = row_base + r;
        float vs = 0.f, vd = 0.f;
#pragma unroll
        for (int ct = 0; ct < NT_; ++ct) {
            float v = acc[ct][r];
            vs = fmaf(v, av[ct], vs);
            vd = fmaf(v, dv[ct], vd);
        }
#pragma unroll
        for (int off = 1; off < 16; off <<= 1) {
            vs += __shfl_xor(vs, off);
            vd += __shfl_xor(vd, off);
        }
        if (n < N) {
            if (li == 0) {
                as_out[n * 2 + bh] = vs;
                ad_out[n * 2 + bh] = vd;
            }
#pragma unroll
            for (int ct = 0; ct < NT_; ++ct)
                Y[(size_t)n * MB + bh * HALF + ct * 16 + li] = f2bf(acc[ct][r]);
        }
    }
}

__device__ __forceinline__ void scan_part_body(const int* __restrict__ deg,
                                               int* __restrict__ tsum, int b) {
    __shared__ int wsh[4];
    int t = threadIdx.x;
    int base = b * STILE + t * 16;
    int sum = 0;
#pragma unroll
    for (int j = 0; j < 16; j += 4) {
        int4 q = *(const int4*)&deg[base + j];
        sum += q.x + q.y + q.z + q.w;
    }
#pragma unroll
    for (int off = 32; off; off >>= 1) sum += __shfl_down(sum, off);
    if ((t & 63) == 0) wsh[t >> 6] = sum;
    __syncthreads();
    if (t == 0) tsum[b] = wsh[0] + wsh[1] + wsh[2] + wsh[3];
}

// ================= kernels =================

// {W prep || histogram(+pos)}
__global__ void k_prep_hist(const float* __restrict__ W1, unsigned short* __restrict__ Wt1,
                            int K1, int M1,
                            const float* __restrict__ W2, unsigned short* __restrict__ Wt2,
                            int K2, int M2, int nPrepBlk,
                            const int* __restrict__ ei, int E, int N,
                            int* __restrict__ deg, int* __restrict__ pos) {
    if ((int)blockIdx.x < nPrepBlk) {
        int i = blockIdx.x * 256 + threadIdx.x;
        int n1 = M1 * K1;
        if (i < n1) {
            int m = i / K1, k = i - m * K1;
            Wt1[i] = f2bf(W1[(size_t)k * M1 + m]);
        } else {
            int j = i - n1;
            if (j < M2 * K2) {
                int m = j / K2, k = j - m * K2;
                Wt2[j] = f2bf(W2[(size_t)k * M2 + m]);
            }
        }
    } else {
        int e = (blockIdx.x - nPrepBlk) * 256 + threadIdx.x;
        if (e >= E + N) return;
        int d = (e < E) ? ei[E + e] : e - E;
        pos[e] = atomicAdd(&deg[d], 1);
    }
}

// {GEMM L1 (split-col) || scan_part}
__global__ __launch_bounds__(256) void k_gemm1_scan(
        const float* __restrict__ X, const unsigned short* __restrict__ Wt,
        unsigned short* __restrict__ Y, float* __restrict__ as_out,
        float* __restrict__ ad_out, const float* __restrict__ a_srcf,
        const float* __restrict__ a_dstf, int N, int GB,
        const int* __restrict__ deg, int* __restrict__ tsum) {
    __shared__ __align__(16) unsigned short lds[128 * (128 + 8)];
    if ((int)blockIdx.x < GB)
        gemm_body<256, 128, float>(X, Wt, Y, as_out, ad_out, a_srcf, a_dstf, N,
                                   blockIdx.x >> 1, blockIdx.x & 1, lds);
    else
        scan_part_body(deg, tsum, blockIdx.x - GB);
}

__global__ __launch_bounds__(256) void scan_final(const int* __restrict__ deg,
                                                  const int* __restrict__ tsum,
                                                  int* __restrict__ rowptr) {
    int b = blockIdx.x, t = threadIdx.x, lane = t & 63, wid = t >> 6;
    int base = b * STILE + t * 16;
    int tpre = 0;
    for (int j = 0; j < b; ++j) tpre += tsum[j];
    int v[16];
    int sum = 0;
#pragma unroll
    for (int j = 0; j < 16; j += 4) {
        int4 q = *(const int4*)&deg[base + j];
        v[j] = q.x; v[j + 1] = q.y; v[j + 2] = q.z; v[j + 3] = q.w;
        sum += q.x + q.y + q.z + q.w;
    }
    int x = sum;
#pragma unroll
    for (int off = 1; off < 64; off <<= 1) {
        int y = __shfl_up(x, off);
        if (lane >= off) x += y;
    }
    __shared__ int wtot[4];
    if (lane == 63) wtot[wid] = x;
    __syncthreads();
    int woff = 0;
    for (int wi = 0; wi < wid; ++wi) woff += wtot[wi];
    int run = tpre + woff + (x - sum);
    int outv[16];
#pragma unroll
    for (int j = 0; j < 16; ++j) { outv[j] = run; run += v[j]; }
#pragma unroll
    for (int j = 0; j < 16; j += 4)
        *(int4*)&rowptr[base + j] = make_int4(outv[j], outv[j+1], outv[j+2], outv[j+3]);
}

// atomic-free CSR fill
__global__ void fill_kernel(const int* __restrict__ ei, int E, int N,
                            const int* __restrict__ rowptr, const int* __restrict__ pos,
                            int* __restrict__ csr_src) {
    int e = blockIdx.x * blockDim.x + threadIdx.x;
    if (e >= E + N) return;
    int s, d;
    if (e < E) { s = ei[e]; d = ei[E + e]; } else { s = d = e - E; }
    csr_src[rowptr[d] + pos[e]] = s;
}

// GEMM L2, split-col
__global__ __launch_bounds__(256) void k_gemm2(
        const unsigned short* __restrict__ X, const unsigned short* __restrict__ Wt,
        unsigned short* __restrict__ Y, float* __restrict__ as_out,
        float* __restrict__ ad_out, const float* __restrict__ a_srcf,
        const float* __restrict__ a_dstf, int N) {
    __shared__ __align__(16) unsigned short lds[64 * (256 + 8)];
    gemm_body<128, 256, unsigned short>(X, Wt, Y, as_out, ad_out, a_srcf, a_dstf, N,
                                        blockIdx.x >> 1, blockIdx.x & 1, lds);
}

// ---------------- fused attn+agg: wave/node, no-max softmax, LDS b128 broadcast ----------------
template<int M, int C, typename TOUT>
__global__ __launch_bounds__(256) void fused_attn_agg(
        const int* __restrict__ rowptr, const int* __restrict__ csr_src,
        const float* __restrict__ as_, const float* __restrict__ ad_,
        const unsigned short* __restrict__ hfeat, const float* __restrict__ bias,
        TOUT* __restrict__ outp, int N, int do_relu) {
    constexpr int VEC = M / 64;   // 4 (L1) or 2 (L2)
    __shared__ __align__(16) uint2 pb0[4][64];  // {byte_off, p_head0}
    __shared__ __align__(16) uint2 pb1[4][64];  // {byte_off, p_head1}
    int n    = (blockIdx.x * blockDim.x + threadIdx.x) >> 6;
    int lane = threadIdx.x & 63;
    int w    = (threadIdx.x >> 6) & 3;
    if (n >= N) return;
    int cbase = lane * VEC;
    int hh    = cbase / C;
    int r0 = rowptr[n], r1 = rowptr[n + 1];
    const float2* as2 = (const float2*)as_;
    float2 adv = ((const float2*)ad_)[n];
    float sa0 = 0.f, sa1 = 0.f;
    float acc[VEC];
#pragma unroll
    for (int v = 0; v < VEC; ++v) acc[v] = 0.f;
    const uint2* ap = (hh == 0) ? pb0[w] : pb1[w];
    const char* hbc = (const char*)hfeat + (size_t)cbase * 2;

    for (int base = r0; base < r1; base += 64) {
        int cnt = min(64, r1 - base);
        int srcl = 0;
        float sc0 = -INFINITY, sc1 = -INFINITY;
        if (lane < cnt) {
            srcl = csr_src[base + lane];
            float2 asv = as2[srcl];
            float e0 = asv.x + adv.x;
            float e1 = asv.y + adv.y;
            sc0 = (e0 > 0.f) ? e0 : NEG_SLOPE * e0;
            sc1 = (e1 > 0.f) ? e1 : NEG_SLOPE * e1;
        }
        float p0 = expf(sc0), p1 = expf(sc1);   // 0 for tail lanes
        sa0 += p0; sa1 += p1;
        unsigned off = (unsigned)srcl * (M * 2);
        pb0[w][lane] = make_uint2(off, __float_as_uint(p0));
        pb1[w][lane] = make_uint2(off, __float_as_uint(p1));
        for (int e = 0; e < cnt; e += 2) {
            uint4 qq = *(const uint4*)&ap[e];
            float pa = __uint_as_float(qq.y);
            float pc = __uint_as_float(qq.w);
            const char* hp0 = hbc + qq.x;
            const char* hp1 = hbc + qq.z;
            if constexpr (VEC == 4) {
                uint2 g0 = *(const uint2*)hp0;
                uint2 g1 = *(const uint2*)hp1;
                acc[0] += pa * bflo(g0.x); acc[1] += pa * bfhi(g0.x);
                acc[2] += pa * bflo(g0.y); acc[3] += pa * bfhi(g0.y);
                acc[0] += pc * bflo(g1.x); acc[1] += pc * bfhi(g1.x);
                acc[2] += pc * bflo(g1.y); acc[3] += pc * bfhi(g1.y);
            } else {
                unsigned g0 = *(const unsigned*)hp0;
                unsigned g1 = *(const unsigned*)hp1;
                acc[0] += pa * bflo(g0); acc[1] += pa * bfhi(g0);
                acc[0] += pc * bflo(g1); acc[1] += pc * bfhi(g1);
            }
        }
    }
#pragma unroll
    for (int off = 32; off; off >>= 1) {
        sa0 += __shfl_xor(sa0, off);
        sa1 += __shfl_xor(sa1, off);
    }
    float ssum = (hh == 0) ? sa0 : sa1;
    float inv = 1.f / (ssum + EPS_F);
    float o[VEC];
#pragma unroll
    for (int v = 0; v < VEC; ++v) {
        float val = acc[v] * inv + bias[cbase + v];
        o[v] = do_relu ? fmaxf(val, 0.f) : val;
    }
    if constexpr (sizeof(TOUT) == 2) {
        unsigned short* op = (unsigned short*)outp + (size_t)n * M + cbase;
        if constexpr (VEC == 4) {
            uint2 pk;
            pk.x = (unsigned)f2bf(o[0]) | ((unsigned)f2bf(o[1]) << 16);
            pk.y = (unsigned)f2bf(o[2]) | ((unsigned)f2bf(o[3]) << 16);
            *(uint2*)op = pk;
        } else {
            *(unsigned*)op = (unsigned)f2bf(o[0]) | ((unsigned)f2bf(o[1]) << 16);
        }
    } else {
        float* op = (float*)outp + (size_t)n * M + cbase;
        if constexpr (VEC == 4) *(float4*)op = make_float4(o[0], o[1], o[2], o[3]);
        else                    *(float2*)op = make_float2(o[0], o[1]);
    }
}

// ---------------- decode: one wave per 2 edges, bf16 z ----------------
__global__ void decode_kernel(const int* __restrict__ pei, int Ep,
                              const unsigned short* __restrict__ z, int D,
                              float* __restrict__ out) {
    int wv   = (blockIdx.x * blockDim.x + threadIdx.x) >> 6;
    int lane = threadIdx.x & 63;
    int half = lane >> 5, sl = lane & 31;   // 32 lanes per edge; sl*4 covers D=128
    int e  = wv * 2 + half;
    int ec = min(e, Ep - 1);
    int a = pei[ec], b = pei[Ep + ec];
    uint2 qa = *(const uint2*)(z + (size_t)a * D + sl * 4);
    uint2 qb = *(const uint2*)(z + (size_t)b * D + sl * 4);
    float s = bflo(qa.x) * bflo(qb.x) + bfhi(qa.x) * bfhi(qb.x)
            + bflo(qa.y) * bflo(qb.y) + bfhi(qa.y) * bfhi(qb.y);
#pragma unroll
    for (int off = 16; off; off >>= 1) s += __shfl_xor(s, off);
    if (sl == 0 && e < Ep) out[e] = s;
}

extern "C" void kernel_launch(void* const* d_in, const int* in_sizes, int n_in,
                              void* d_out, int out_size, void* d_ws, size_t ws_size,
                              hipStream_t stream) {
    const float* x   = (const float*)d_in[0];
    const int*   ei  = (const int*)d_in[1];
    const int*   pei = (const int*)d_in[2];
    const float* W1  = (const float*)d_in[3];
    const float* a1s = (const float*)d_in[4];
    const float* a1d = (const float*)d_in[5];
    const float* b1  = (const float*)d_in[6];
    const float* W2  = (const float*)d_in[7];
    const float* a2s = (const float*)d_in[8];
    const float* a2d = (const float*)d_in[9];
    const float* b2  = (const float*)d_in[10];
    float* out = (float*)d_out;

    const int M1  = in_sizes[6];            // 256
    const int Fin = in_sizes[3] / M1;       // 128
    const int N   = in_sizes[0] / Fin;      // 50000
    const int E   = in_sizes[1] / 2;        // 800000
    const int Ep  = in_sizes[2] / 2;        // 100000
    const int M2  = in_sizes[10];           // 128
    const int Etot = E + N;
    const int NT  = (N + STILE - 1) / STILE;   // scan tiles (13)

    // workspace layout (16B-aligned sections)
    unsigned short* hbf  = (unsigned short*)d_ws;         // N*M1 bf16 gather table
    unsigned short* h1bf = hbf + (size_t)N * M1;          // N*M1 bf16 h1
    unsigned short* zbf  = h1bf + (size_t)N * M1;         // N*M2 bf16 z
    float* as_     = (float*)(zbf + (size_t)N * M2);      // N*2
    float* ad_     = as_ + (size_t)N * 2;                 // N*2
    int*   deg     = (int*)(ad_ + (size_t)N * 2);         // NT*STILE (padded)
    int*   rowptr  = deg + (size_t)NT * STILE;            // NT*STILE (padded; rowptr[N] valid)
    int*   tsum    = rowptr + (size_t)NT * STILE;         // 64
    int*   pos     = tsum + 64;                           // Etot
    int*   csr_src = pos + Etot;                          // Etot
    unsigned short* wt1 = (unsigned short*)(csr_src + Etot);   // M1*Fin bf16 (W1^T)
    unsigned short* wt2 = wt1 + (size_t)M1 * Fin;              // M2*M1 bf16 (W2^T)

    dim3 blk256(256);

    // ---- node 1: zero deg ----
    hipMemsetAsync(deg, 0, (size_t)NT * STILE * sizeof(int), stream);

    // ---- node 2: {W prep || histogram(+pos)} ----
    int nPrepBlk = (M1 * Fin + M2 * M1 + 255) / 256;
    int nHistBlk = (Etot + 255) / 256;
    k_prep_hist<<<nPrepBlk + nHistBlk, blk256, 0, stream>>>(
        W1, wt1, Fin, M1, W2, wt2, M1, M2, nPrepBlk, ei, E, N, deg, pos);

    // ---- node 3: {GEMM L1 (split-col) || scan_part} ----
    int GB = 2 * ((N + 63) / 64);
    k_gemm1_scan<<<GB + NT, blk256, 0, stream>>>(
        x, wt1, hbf, as_, ad_, a1s, a1d, N, GB, deg, tsum);

    // ---- node 4: scan_final ----
    scan_final<<<NT, blk256, 0, stream>>>(deg, tsum, rowptr);

    // ---- node 5: atomic-free fill ----
    fill_kernel<<<nHistBlk, blk256, 0, stream>>>(ei, E, N, rowptr, pos, csr_src);

    // ---- node 6: attn L1 -> bf16 h1 ----
    fused_attn_agg<256, 128, unsigned short><<<(N + 3) / 4, blk256, 0, stream>>>(
        rowptr, csr_src, as_, ad_, hbf, b1, h1bf, N, 1);

    // ---- node 7: GEMM L2 (split-col) ----
    k_gemm2<<<2 * ((N + 63) / 64), blk256, 0, stream>>>(
        h1bf, wt2, hbf, as_, ad_, a2s, a2d, N);

    // ---- node 8: attn L2 -> bf16 z ----
    fused_attn_agg<128, 64, unsigned short><<<(N + 3) / 4, blk256, 0, stream>>>(
        rowptr, csr_src, as_, ad_, hbf, b2, zbf, N, 0);

    // ---- node 9: decode (bf16 z, wave per 2 edges) ----
    {
        int waves = (Ep + 1) / 2;
        decode_kernel<<<(waves * 64 + 255) / 256, blk256, 0, stream>>>(
            pei, Ep, zbf, M2, out);
    }
}